// Round 1
// baseline (12068.568 us; speedup 1.0000x reference)
//
#include <hip/hip_runtime.h>
#include <cstddef>

#define BB 4
#define TT 1024
#define DMODEL 512
#define DFF 2048
#define NHEAD 8
#define HDIM 64
#define NTOK (BB*TT)
#define NLAYER 6
#define MFOUT 256

// ---------------- generic f32 GEMM ----------------
// out[m][n] = (res ? res[m*N+n] : 0) + act(sum_k A[m][k]*W[k][n] + bias[n])
// act = prelu(alpha[0]) if alpha else identity.
// Concat input: columns k >= K1 come from A2 (row stride lda2) when A2 != null.
__global__ __launch_bounds__(256)
void gemm_f32(const float* __restrict__ A, const float* __restrict__ A2, int K1, int lda, int lda2,
              const float* __restrict__ W, const float* __restrict__ bias,
              const float* __restrict__ alpha, const float* __restrict__ res,
              float* __restrict__ out, int N, int K)
{
    __shared__ __align__(16) float As[16][68];
    __shared__ __align__(16) float Ws[16][68];
    const int tid = threadIdx.x;
    const int tx = tid & 15;
    const int ty = tid >> 4;
    const int m0 = blockIdx.y * 64;
    const int n0 = blockIdx.x * 64;
    float acc[4][4] = {};
    for (int k0 = 0; k0 < K; k0 += 16) {
        #pragma unroll
        for (int i = 0; i < 4; i++) {
            int idx = tid + i * 256;
            int r = idx >> 4, c = idx & 15;
            int gk = k0 + c;
            float v;
            if (A2 != nullptr && gk >= K1)
                v = A2[(size_t)(m0 + r) * lda2 + (gk - K1)];
            else
                v = A[(size_t)(m0 + r) * lda + gk];
            As[c][r] = v;
        }
        #pragma unroll
        for (int i = 0; i < 4; i++) {
            int idx = tid + i * 256;
            int r = idx >> 6, c = idx & 63;
            Ws[r][c] = W[(size_t)(k0 + r) * N + n0 + c];
        }
        __syncthreads();
        #pragma unroll
        for (int kk = 0; kk < 16; kk++) {
            float a[4], w[4];
            *(float4*)a = *(const float4*)&As[kk][ty * 4];
            *(float4*)w = *(const float4*)&Ws[kk][tx * 4];
            #pragma unroll
            for (int i = 0; i < 4; i++)
                #pragma unroll
                for (int j = 0; j < 4; j++)
                    acc[i][j] = fmaf(a[i], w[j], acc[i][j]);
        }
        __syncthreads();
    }
    const float al = alpha ? alpha[0] : 0.f;
    const bool act = (alpha != nullptr);
    #pragma unroll
    for (int i = 0; i < 4; i++) {
        const int gm = m0 + ty * 4 + i;
        const int gn = n0 + tx * 4;
        float v[4];
        #pragma unroll
        for (int j = 0; j < 4; j++) {
            float xv = acc[i][j];
            if (bias) xv += bias[gn + j];
            if (act) xv = (xv >= 0.f) ? xv : al * xv;
            v[j] = xv;
        }
        if (res) {
            const float4 rv = *(const float4*)&res[(size_t)gm * N + gn];
            v[0] += rv.x; v[1] += rv.y; v[2] += rv.z; v[3] += rv.w;
        }
        float4 o; o.x = v[0]; o.y = v[1]; o.z = v[2]; o.w = v[3];
        *(float4*)&out[(size_t)gm * N + gn] = o;
    }
}

// ---------------- LayerNorm: one wave per token ----------------
__global__ __launch_bounds__(64)
void ln_kernel(const float* __restrict__ x, const float* __restrict__ g,
               const float* __restrict__ b, float* __restrict__ out)
{
    const int token = blockIdx.x;
    const int lane = threadIdx.x;
    const float* row = x + (size_t)token * DMODEL;
    float v[8];
    *(float4*)&v[0] = *(const float4*)&row[lane * 4];
    *(float4*)&v[4] = *(const float4*)&row[256 + lane * 4];
    float s = 0.f, s2 = 0.f;
    #pragma unroll
    for (int i = 0; i < 8; i++) { s += v[i]; s2 += v[i] * v[i]; }
    #pragma unroll
    for (int off = 1; off < 64; off <<= 1) {
        s  += __shfl_xor(s, off);
        s2 += __shfl_xor(s2, off);
    }
    const float mean = s * (1.f / DMODEL);
    const float var  = s2 * (1.f / DMODEL) - mean * mean;
    const float rstd = rsqrtf(var + 1e-5f);
    float* orow = out + (size_t)token * DMODEL;
    #pragma unroll
    for (int hh = 0; hh < 2; hh++) {
        const int base = hh * 256 + lane * 4;
        const float4 gv = *(const float4*)&g[base];
        const float4 bv = *(const float4*)&b[base];
        float4 o;
        o.x = (v[hh*4+0] - mean) * rstd * gv.x + bv.x;
        o.y = (v[hh*4+1] - mean) * rstd * gv.y + bv.y;
        o.z = (v[hh*4+2] - mean) * rstd * gv.z + bv.z;
        o.w = (v[hh*4+3] - mean) * rstd * gv.w + bv.w;
        *(float4*)&orow[base] = o;
    }
}

// ---------------- attention key-validity mask ----------------
__global__ __launch_bounds__(64)
void mask_kernel(const float* __restrict__ mask_in, float* __restrict__ mk)
{
    const int token = blockIdx.x;
    const int lane = threadIdx.x;
    const float* row = mask_in + (size_t)token * DMODEL;
    const float4 a = *(const float4*)&row[lane * 4];
    const float4 c = *(const float4*)&row[256 + lane * 4];
    float s = a.x + a.y + a.z + a.w + c.x + c.y + c.z + c.w;
    #pragma unroll
    for (int off = 1; off < 64; off <<= 1) s += __shfl_xor(s, off);
    if (lane == 0) mk[token] = (s > 0.f) ? 0.f : -1e9f;
}

// ---------------- relative position table E: (2047, 64) ----------------
__global__ __launch_bounds__(64)
void e_kernel(const float* __restrict__ w1, const float* __restrict__ b1,
              const float* __restrict__ a1, const float* __restrict__ w2,
              const float* __restrict__ b2, float* __restrict__ E)
{
    __shared__ float t1[DMODEL];
    const int r = blockIdx.x;
    const int lane = threadIdx.x;
    const float rel = (float)r - 1023.f;
    const float al = a1[0];
    for (int j = lane; j < DMODEL; j += 64) {
        float v = rel * w1[j] + b1[j];
        t1[j] = (v >= 0.f) ? v : al * v;
    }
    __syncthreads();
    float acc = b2[lane];
    for (int j = 0; j < DMODEL; j++)
        acc = fmaf(t1[j], w2[j * HDIM + lane], acc);
    E[(size_t)r * HDIM + lane] = acc;
}

// ---------------- keyframe encoder layer 1 (K=2) ----------------
__global__ __launch_bounds__(256)
void kf1_kernel(const float* __restrict__ p, const float* __restrict__ w1,
                const float* __restrict__ b1, const float* __restrict__ a1,
                float* __restrict__ out)
{
    const int idx = blockIdx.x * 256 + threadIdx.x;
    const int m = idx >> 9, n = idx & 511;
    float v = fmaf(p[m*2], w1[n], fmaf(p[m*2+1], w1[DMODEL + n], b1[n]));
    out[idx] = (v >= 0.f) ? v : a1[0] * v;
}

// ---------------- flash attention with relative-position skew ----------------
// 1 wave = 64 q rows of one (b,h). att[q][k] = (Q.K[k] + Q.E[k-q+1023])*scale + mask[k]
__global__ __launch_bounds__(64, 1)
void attn_kernel(const float* __restrict__ qb, const float* __restrict__ kb,
                 const float* __restrict__ vb, const float* __restrict__ E,
                 const float* __restrict__ mk, float* __restrict__ ob)
{
    __shared__ __align__(16) float KV[64][64];   // K tile, then restaged as V tile
    __shared__ __align__(16) float Es[127][68];  // stride 68: breaks 64-float bank aliasing, keeps 16B align
    __shared__ __align__(16) float Ss[64][64];   // scores: [k_local][lane(q)]
    const int lane = threadIdx.x;
    const int q0 = blockIdx.x * 64;
    const int hh = blockIdx.y;
    const int bb = blockIdx.z;
    const size_t base = (size_t)bb * TT * DMODEL + (size_t)hh * HDIM;

    float qreg[64];
    {
        const float* qrow = qb + base + (size_t)(q0 + lane) * DMODEL;
        #pragma unroll
        for (int d = 0; d < 64; d += 4)
            *(float4*)&qreg[d] = *(const float4*)&qrow[d];
    }
    float acc[64];
    #pragma unroll
    for (int d = 0; d < 64; d++) acc[d] = 0.f;
    float mrun = -1e30f, lrun = 0.f;

    for (int kt = 0; kt < 16; kt++) {
        const size_t kvbase = base + (size_t)kt * 64 * DMODEL;
        __syncthreads();
        // stage K tile (64 rows x 64 cols), coalesced float4
        #pragma unroll
        for (int i = 0; i < 16; i++) {
            const int f = (lane + i * 64) * 4;
            const int r = f >> 6, d = f & 63;
            *(float4*)&KV[r][d] = *(const float4*)&kb[kvbase + (size_t)r * DMODEL + d];
        }
        // stage 127 E rows: global row rbase+r == (k - q + 1023) for this tile pair range
        const int rbase = kt * 64 - q0 + 960;
        #pragma unroll
        for (int i = 0; i < 32; i++) {
            const int f4 = lane + i * 64;
            if (f4 < 2032) {
                const int f = f4 * 4;
                const int r = f >> 6, d = f & 63;
                *(float4*)&Es[r][d] = *(const float4*)&E[(size_t)(rbase + r) * HDIM + d];
            }
        }
        __syncthreads();
        // phase 1: scores into Ss, track per-lane tile max
        const float* mrow = mk + bb * TT + kt * 64;
        float tmax = -1e30f;
        for (int kl = 0; kl < 64; kl++) {
            const float* kr = &KV[kl][0];                 // broadcast across lanes
            const float* er = &Es[kl + 63 - lane][0];     // per-lane diagonal row
            float s0 = 0.f, s1 = 0.f;
            #pragma unroll
            for (int d = 0; d < 64; d += 4) {
                const float4 kv = *(const float4*)(kr + d);
                const float4 ev = *(const float4*)(er + d);
                s0 = fmaf(qreg[d+0], kv.x, s0);  s1 = fmaf(qreg[d+0], ev.x, s1);
                s0 = fmaf(qreg[d+1], kv.y, s0);  s1 = fmaf(qreg[d+1], ev.y, s1);
                s0 = fmaf(qreg[d+2], kv.z, s0);  s1 = fmaf(qreg[d+2], ev.z, s1);
                s0 = fmaf(qreg[d+3], kv.w, s0);  s1 = fmaf(qreg[d+3], ev.w, s1);
            }
            const float sv = (s0 + s1) * 0.125f + mrow[kl];
            Ss[kl][lane] = sv;
            tmax = fmaxf(tmax, sv);
        }
        // online-softmax rescale (once per tile)
        const float mn = fmaxf(mrun, tmax);
        const float corr = __expf(mrun - mn);
        mrun = mn;
        lrun *= corr;
        #pragma unroll
        for (int d = 0; d < 64; d++) acc[d] *= corr;
        __syncthreads();
        // restage V over the K tile
        #pragma unroll
        for (int i = 0; i < 16; i++) {
            const int f = (lane + i * 64) * 4;
            const int r = f >> 6, d = f & 63;
            *(float4*)&KV[r][d] = *(const float4*)&vb[kvbase + (size_t)r * DMODEL + d];
        }
        __syncthreads();
        // phase 2: PV accumulate
        for (int kl = 0; kl < 64; kl++) {
            const float p = __expf(Ss[kl][lane] - mn);
            lrun += p;
            const float* vr = &KV[kl][0];
            #pragma unroll
            for (int d = 0; d < 64; d += 4) {
                const float4 vv = *(const float4*)(vr + d);
                acc[d+0] = fmaf(p, vv.x, acc[d+0]);
                acc[d+1] = fmaf(p, vv.y, acc[d+1]);
                acc[d+2] = fmaf(p, vv.z, acc[d+2]);
                acc[d+3] = fmaf(p, vv.w, acc[d+3]);
            }
        }
    }
    const float inv = 1.f / lrun;
    float* orow = ob + base + (size_t)(q0 + lane) * DMODEL;
    #pragma unroll
    for (int d = 0; d < 64; d += 4) {
        float4 o;
        o.x = acc[d+0]*inv; o.y = acc[d+1]*inv; o.z = acc[d+2]*inv; o.w = acc[d+3]*inv;
        *(float4*)&orow[d] = o;
    }
}

extern "C" void kernel_launch(void* const* d_in, const int* in_sizes, int n_in,
                              void* d_out, int out_size, void* d_ws, size_t ws_size,
                              hipStream_t stream)
{
    const float* x       = (const float*)d_in[0];
    const float* mask_in = (const float*)d_in[1];
    const float* p_kf    = (const float*)d_in[2];
    const float* enc_w1  = (const float*)d_in[3];
    const float* enc_b1  = (const float*)d_in[4];
    const float* enc_a1  = (const float*)d_in[5];
    const float* enc_w2  = (const float*)d_in[6];
    const float* enc_b2  = (const float*)d_in[7];
    const float* enc_a2  = (const float*)d_in[8];
    const float* kf_w1   = (const float*)d_in[9];
    const float* kf_b1   = (const float*)d_in[10];
    const float* kf_a    = (const float*)d_in[11];
    const float* kf_w2   = (const float*)d_in[12];
    const float* kf_b2   = (const float*)d_in[13];
    const float* rel_w1  = (const float*)d_in[14];
    const float* rel_b1  = (const float*)d_in[15];
    const float* rel_a   = (const float*)d_in[16];
    const float* rel_w2  = (const float*)d_in[17];
    const float* rel_b2  = (const float*)d_in[18];
    const float* ln_g    = (const float*)d_in[19];
    const float* ln_b    = (const float*)d_in[20];
    const float* wq      = (const float*)d_in[21];
    const float* wk      = (const float*)d_in[22];
    const float* wv      = (const float*)d_in[23];
    const float* wo      = (const float*)d_in[24];
    const float* wob     = (const float*)d_in[25];
    const float* fw1     = (const float*)d_in[26];
    const float* fb1     = (const float*)d_in[27];
    const float* fa      = (const float*)d_in[28];
    const float* fw2     = (const float*)d_in[29];
    const float* fb2     = (const float*)d_in[30];
    const float* dw1     = (const float*)d_in[31];
    const float* db1     = (const float*)d_in[32];
    const float* da      = (const float*)d_in[33];
    const float* dw2     = (const float*)d_in[34];
    const float* db2     = (const float*)d_in[35];
    float* out = (float*)d_out;

    // workspace layout (floats): ~84.4 MB total
    float* ws  = (float*)d_ws;
    float* h   = ws;                  // NTOK*DMODEL
    float* hn  = h  + (size_t)NTOK * DMODEL;
    float* qb  = hn + (size_t)NTOK * DMODEL;
    float* kb  = qb + (size_t)NTOK * DMODEL;   // also holds pe_kf during encode
    float* vb  = kb + (size_t)NTOK * DMODEL;
    float* ob  = vb + (size_t)NTOK * DMODEL;
    float* mid = ob + (size_t)NTOK * DMODEL;   // NTOK*DFF
    float* E   = mid + (size_t)NTOK * DFF;     // 2047*64
    float* mk  = E  + (size_t)2048 * HDIM;     // NTOK

    const dim3 blk256(256), blk64(64);
    const dim3 g512(512/64, NTOK/64);
    const dim3 g2048(2048/64, NTOK/64);
    const dim3 g256(256/64, NTOK/64);

    e_kernel<<<dim3(2047), blk64, 0, stream>>>(rel_w1, rel_b1, rel_a, rel_w2, rel_b2, E);
    mask_kernel<<<dim3(NTOK), blk64, 0, stream>>>(mask_in, mk);
    kf1_kernel<<<dim3(NTOK*DMODEL/256), blk256, 0, stream>>>(p_kf, kf_w1, kf_b1, kf_a, qb);
    // pe_kf = prelu_mid @ kf_w2 + kf_b2  -> kb
    gemm_f32<<<g512, blk256, 0, stream>>>(qb, nullptr, 0, DMODEL, 0, kf_w2, kf_b2,
                                          nullptr, nullptr, kb, DMODEL, DMODEL);
    // enc layer1: prelu([x, mask] @ enc_w1 + b1, a1) -> mid
    gemm_f32<<<g512, blk256, 0, stream>>>(x, mask_in, DMODEL, DMODEL, DMODEL, enc_w1, enc_b1,
                                          enc_a1, nullptr, mid, DMODEL, 2*DMODEL);
    // h = prelu(mid @ enc_w2 + b2, a2) + pe_kf
    gemm_f32<<<g512, blk256, 0, stream>>>(mid, nullptr, 0, DMODEL, 0, enc_w2, enc_b2,
                                          enc_a2, kb, h, DMODEL, DMODEL);

    for (int i = 0; i < NLAYER; i++) {
        const size_t wofs = (size_t)i * DMODEL * DMODEL;
        ln_kernel<<<dim3(NTOK), blk64, 0, stream>>>(h, ln_g, ln_b, hn);
        gemm_f32<<<g512, blk256, 0, stream>>>(hn, nullptr, 0, DMODEL, 0, wq + wofs, nullptr,
                                              nullptr, nullptr, qb, DMODEL, DMODEL);
        gemm_f32<<<g512, blk256, 0, stream>>>(hn, nullptr, 0, DMODEL, 0, wk + wofs, nullptr,
                                              nullptr, nullptr, kb, DMODEL, DMODEL);
        gemm_f32<<<g512, blk256, 0, stream>>>(hn, nullptr, 0, DMODEL, 0, wv + wofs, nullptr,
                                              nullptr, nullptr, vb, DMODEL, DMODEL);
        attn_kernel<<<dim3(TT/64, NHEAD, BB), blk64, 0, stream>>>(qb, kb, vb, E, mk, ob);
        gemm_f32<<<g512, blk256, 0, stream>>>(ob, nullptr, 0, DMODEL, 0, wo + wofs, wob + (size_t)i*DMODEL,
                                              nullptr, h, h, DMODEL, DMODEL);
        ln_kernel<<<dim3(NTOK), blk64, 0, stream>>>(h, ln_g, ln_b, hn);
        gemm_f32<<<g2048, blk256, 0, stream>>>(hn, nullptr, 0, DMODEL, 0,
                                               fw1 + (size_t)i*DMODEL*DFF, fb1 + (size_t)i*DFF,
                                               fa + i, nullptr, mid, DFF, DMODEL);
        gemm_f32<<<g512, blk256, 0, stream>>>(mid, nullptr, 0, DFF, 0,
                                              fw2 + (size_t)i*DFF*DMODEL, fb2 + (size_t)i*DMODEL,
                                              nullptr, h, h, DMODEL, DFF);
    }
    // decoder
    gemm_f32<<<g512, blk256, 0, stream>>>(h, nullptr, 0, DMODEL, 0, dw1, db1,
                                          da, nullptr, qb, DMODEL, DMODEL);
    gemm_f32<<<g256, blk256, 0, stream>>>(qb, nullptr, 0, DMODEL, 0, dw2, db2,
                                          nullptr, nullptr, out, MFOUT, DMODEL);
}

// Round 3
// 3902.514 us; speedup vs baseline: 3.0925x; 3.0925x over previous
//
#include <hip/hip_runtime.h>
#include <cstddef>

#define BB 4
#define TT 1024
#define DMODEL 512
#define DFF 2048
#define NHEAD 8
#define HDIM 64
#define NTOK (BB*TT)
#define NLAYER 6
#define MFOUT 256

typedef __attribute__((ext_vector_type(8))) _Float16 f16x8;
typedef __attribute__((ext_vector_type(4))) float f32x4;
#define MFMAH(a,b,c) __builtin_amdgcn_mfma_f32_16x16x32_f16(a,b,c,0,0,0)

union F16x4 { _Float16 h[4]; uint2 u; };

__device__ __forceinline__ void f16split(float v, _Float16& h, _Float16& l) {
    h = (_Float16)v;
    l = (_Float16)(v - (float)h);
}

// ---------------- generic f32 GEMM ----------------
__global__ __launch_bounds__(256)
void gemm_f32(const float* __restrict__ A, const float* __restrict__ A2, int K1, int lda, int lda2,
              const float* __restrict__ W, const float* __restrict__ bias,
              const float* __restrict__ alpha, const float* __restrict__ res,
              float* __restrict__ out, int N, int K)
{
    __shared__ __align__(16) float As[16][68];
    __shared__ __align__(16) float Ws[16][68];
    const int tid = threadIdx.x;
    const int tx = tid & 15;
    const int ty = tid >> 4;
    const int m0 = blockIdx.y * 64;
    const int n0 = blockIdx.x * 64;
    float acc[4][4] = {};
    for (int k0 = 0; k0 < K; k0 += 16) {
        #pragma unroll
        for (int i = 0; i < 4; i++) {
            int idx = tid + i * 256;
            int r = idx >> 4, c = idx & 15;
            int gk = k0 + c;
            float v;
            if (A2 != nullptr && gk >= K1)
                v = A2[(size_t)(m0 + r) * lda2 + (gk - K1)];
            else
                v = A[(size_t)(m0 + r) * lda + gk];
            As[c][r] = v;
        }
        #pragma unroll
        for (int i = 0; i < 4; i++) {
            int idx = tid + i * 256;
            int r = idx >> 6, c = idx & 63;
            Ws[r][c] = W[(size_t)(k0 + r) * N + n0 + c];
        }
        __syncthreads();
        #pragma unroll
        for (int kk = 0; kk < 16; kk++) {
            float a[4], w[4];
            *(float4*)a = *(const float4*)&As[kk][ty * 4];
            *(float4*)w = *(const float4*)&Ws[kk][tx * 4];
            #pragma unroll
            for (int i = 0; i < 4; i++)
                #pragma unroll
                for (int j = 0; j < 4; j++)
                    acc[i][j] = fmaf(a[i], w[j], acc[i][j]);
        }
        __syncthreads();
    }
    const float al = alpha ? alpha[0] : 0.f;
    const bool act = (alpha != nullptr);
    #pragma unroll
    for (int i = 0; i < 4; i++) {
        const int gm = m0 + ty * 4 + i;
        const int gn = n0 + tx * 4;
        float v[4];
        #pragma unroll
        for (int j = 0; j < 4; j++) {
            float xv = acc[i][j];
            if (bias) xv += bias[gn + j];
            if (act) xv = (xv >= 0.f) ? xv : al * xv;
            v[j] = xv;
        }
        if (res) {
            const float4 rv = *(const float4*)&res[(size_t)gm * N + gn];
            v[0] += rv.x; v[1] += rv.y; v[2] += rv.z; v[3] += rv.w;
        }
        float4 o; o.x = v[0]; o.y = v[1]; o.z = v[2]; o.w = v[3];
        *(float4*)&out[(size_t)gm * N + gn] = o;
    }
}

// ---------------- LayerNorm: one wave per token ----------------
__global__ __launch_bounds__(64)
void ln_kernel(const float* __restrict__ x, const float* __restrict__ g,
               const float* __restrict__ b, float* __restrict__ out)
{
    const int token = blockIdx.x;
    const int lane = threadIdx.x;
    const float* row = x + (size_t)token * DMODEL;
    float v[8];
    *(float4*)&v[0] = *(const float4*)&row[lane * 4];
    *(float4*)&v[4] = *(const float4*)&row[256 + lane * 4];
    float s = 0.f, s2 = 0.f;
    #pragma unroll
    for (int i = 0; i < 8; i++) { s += v[i]; s2 += v[i] * v[i]; }
    #pragma unroll
    for (int off = 1; off < 64; off <<= 1) {
        s  += __shfl_xor(s, off);
        s2 += __shfl_xor(s2, off);
    }
    const float mean = s * (1.f / DMODEL);
    const float var  = s2 * (1.f / DMODEL) - mean * mean;
    const float rstd = rsqrtf(var + 1e-5f);
    float* orow = out + (size_t)token * DMODEL;
    #pragma unroll
    for (int hh = 0; hh < 2; hh++) {
        const int base = hh * 256 + lane * 4;
        const float4 gv = *(const float4*)&g[base];
        const float4 bv = *(const float4*)&b[base];
        float4 o;
        o.x = (v[hh*4+0] - mean) * rstd * gv.x + bv.x;
        o.y = (v[hh*4+1] - mean) * rstd * gv.y + bv.y;
        o.z = (v[hh*4+2] - mean) * rstd * gv.z + bv.z;
        o.w = (v[hh*4+3] - mean) * rstd * gv.w + bv.w;
        *(float4*)&orow[base] = o;
    }
}

// ---------------- attention key-validity mask ----------------
__global__ __launch_bounds__(64)
void mask_kernel(const float* __restrict__ mask_in, float* __restrict__ mk)
{
    const int token = blockIdx.x;
    const int lane = threadIdx.x;
    const float* row = mask_in + (size_t)token * DMODEL;
    const float4 a = *(const float4*)&row[lane * 4];
    const float4 c = *(const float4*)&row[256 + lane * 4];
    float s = a.x + a.y + a.z + a.w + c.x + c.y + c.z + c.w;
    #pragma unroll
    for (int off = 1; off < 64; off <<= 1) s += __shfl_xor(s, off);
    if (lane == 0) mk[token] = (s > 0.f) ? 0.f : -1e9f;
}

// ---------------- relative position table E -> f16 hi/lo (2047, 64) ----------------
__global__ __launch_bounds__(64)
void e_kernel(const float* __restrict__ w1, const float* __restrict__ b1,
              const float* __restrict__ a1, const float* __restrict__ w2,
              const float* __restrict__ b2,
              _Float16* __restrict__ Ehi, _Float16* __restrict__ Elo)
{
    __shared__ float t1[DMODEL];
    const int r = blockIdx.x;
    const int lane = threadIdx.x;
    const float rel = (float)r - 1023.f;
    const float al = a1[0];
    for (int j = lane; j < DMODEL; j += 64) {
        float v = rel * w1[j] + b1[j];
        t1[j] = (v >= 0.f) ? v : al * v;
    }
    __syncthreads();
    float acc = b2[lane];
    for (int j = 0; j < DMODEL; j++)
        acc = fmaf(t1[j], w2[j * HDIM + lane], acc);
    _Float16 h, l;
    f16split(acc, h, l);
    Ehi[(size_t)r * HDIM + lane] = h;
    Elo[(size_t)r * HDIM + lane] = l;
}

// ---------------- keyframe encoder layer 1 (K=2) ----------------
__global__ __launch_bounds__(256)
void kf1_kernel(const float* __restrict__ p, const float* __restrict__ w1,
                const float* __restrict__ b1, const float* __restrict__ a1,
                float* __restrict__ out)
{
    const int idx = blockIdx.x * 256 + threadIdx.x;
    const int m = idx >> 9, n = idx & 511;
    float v = fmaf(p[m*2], w1[n], fmaf(p[m*2+1], w1[DMODEL + n], b1[n]));
    out[idx] = (v >= 0.f) ? v : a1[0] * v;
}

// ---------------- MFMA flash attention, f16 hi/lo precision ----------------
// Block = (qtile 64, head, batch), 256 threads = 4 waves; wave w owns q rows [16w,16w+16).
// S = QK^T single-pass f16 (err ~7e-4 logits).
// rel R[q][j] = Q.E[row] via Qh.Eh + Qh.El into R, Qm.Eh into R2 (Qm = (Q-Qh)*1024,
// avoids f16 denormal flush of the low part); R += R2/1024. err ~1e-3 logits.
// PV 3-pass: Ph.Vh + Pl.Vh + Ph.Vl. E hi/lo fragments read direct from global (L2).
__global__ __launch_bounds__(256, 2)
void attn_mfma(const float* __restrict__ qb, const float* __restrict__ kb,
               const float* __restrict__ vb, const _Float16* __restrict__ Ehi,
               const _Float16* __restrict__ Elo, const float* __restrict__ mk,
               float* __restrict__ ob)
{
    __shared__ __align__(16) _Float16 Ks [64*72];  // K tile (also Q hi prestage)
    __shared__ __align__(16) _Float16 Vth[64*72];  // V^T hi (also Q mid prestage)
    __shared__ __align__(16) _Float16 Vtl[64*72];  // V^T lo
    __shared__ __align__(16) _Float16 Phs[64*72];  // P hi
    __shared__ __align__(16) _Float16 Pls[64*72];  // P lo

    const int tid = threadIdx.x;
    const int lane = tid & 63;
    const int w = tid >> 6;
    const int quad = lane >> 4;
    const int c = lane & 15;
    const int q0 = blockIdx.x * 64;
    const int hh = blockIdx.y;
    const int bb = blockIdx.z;
    const size_t base = (size_t)bb * TT * DMODEL + (size_t)hh * HDIM;
    const float* mkp = mk + bb * TT;

    // ---- prestage Q: hi into Ks, mid=(Q-hi)*1024 into Vth ----
    #pragma unroll
    for (int i = 0; i < 4; i++) {
        const int f4 = tid + i * 256;
        const int r = f4 >> 4, dc = (f4 & 15) * 4;
        const float4 v = *(const float4*)&qb[base + (size_t)(q0 + r) * DMODEL + dc];
        F16x4 ph, pm;
        const float vv[4] = {v.x, v.y, v.z, v.w};
        #pragma unroll
        for (int j = 0; j < 4; j++) {
            ph.h[j] = (_Float16)vv[j];
            pm.h[j] = (_Float16)((vv[j] - (float)ph.h[j]) * 1024.f);
        }
        *(uint2*)&Ks [r * 72 + dc] = ph.u;
        *(uint2*)&Vth[r * 72 + dc] = pm.u;
    }
    __syncthreads();
    f16x8 qh[2], qm[2];
    #pragma unroll
    for (int s = 0; s < 2; s++) {
        qh[s] = *(const f16x8*)&Ks [(16 * w + c) * 72 + s * 32 + quad * 8];
        qm[s] = *(const f16x8*)&Vth[(16 * w + c) * 72 + s * 32 + quad * 8];
    }
    __syncthreads();

    f32x4 O[4];
    #pragma unroll
    for (int dt = 0; dt < 4; dt++) { O[dt][0]=0.f; O[dt][1]=0.f; O[dt][2]=0.f; O[dt][3]=0.f; }
    float mrun[4] = {-1e30f, -1e30f, -1e30f, -1e30f};
    float lrun[4] = {0.f, 0.f, 0.f, 0.f};
    const int Jb = 48 - 16 * w;

    for (int kt = 0; kt < 16; kt++) {
        const int k0 = kt * 64;
        const size_t kvbase = base + (size_t)k0 * DMODEL;
        const int rbase = k0 - q0 + 960;
        // ---- stage K (f16), V^T hi/lo ----
        #pragma unroll
        for (int i = 0; i < 4; i++) {
            const int f4 = tid + i * 256;
            const int r = f4 >> 4, dc = (f4 & 15) * 4;
            const float4 kv = *(const float4*)&kb[kvbase + (size_t)r * DMODEL + dc];
            F16x4 pk;
            pk.h[0] = (_Float16)kv.x; pk.h[1] = (_Float16)kv.y;
            pk.h[2] = (_Float16)kv.z; pk.h[3] = (_Float16)kv.w;
            *(uint2*)&Ks[r * 72 + dc] = pk.u;
            const float4 vv = *(const float4*)&vb[kvbase + (size_t)r * DMODEL + dc];
            const float va[4] = {vv.x, vv.y, vv.z, vv.w};
            #pragma unroll
            for (int j = 0; j < 4; j++) {
                _Float16 vh_, vl_;
                f16split(va[j], vh_, vl_);
                Vth[(dc + j) * 72 + r] = vh_;
                Vtl[(dc + j) * 72 + r] = vl_;
            }
        }
        __syncthreads();

        // ---- S = Q K^T (single-pass f16) ----
        f32x4 S[4];
        #pragma unroll
        for (int t = 0; t < 4; t++) { S[t][0]=0.f; S[t][1]=0.f; S[t][2]=0.f; S[t][3]=0.f; }
        #pragma unroll
        for (int t = 0; t < 4; t++)
            #pragma unroll
            for (int s = 0; s < 2; s++) {
                const f16x8 kf = *(const f16x8*)&Ks[(16*t + c) * 72 + s*32 + quad*8];
                S[t] = MFMAH(qh[s], kf, S[t]);
            }
        // ---- rel term: R = Qh.Eh + Qh.El ; R2 = Qm.Eh ----
        f32x4 R[5], R2[5];
        #pragma unroll
        for (int u = 0; u < 5; u++) {
            R[u][0]=0.f; R[u][1]=0.f; R[u][2]=0.f; R[u][3]=0.f;
            R2[u][0]=0.f; R2[u][1]=0.f; R2[u][2]=0.f; R2[u][3]=0.f;
        }
        #pragma unroll
        for (int u = 0; u < 5; u++) {
            int gr = rbase + Jb + 16 * u + c;
            gr = gr < 0 ? 0 : (gr > 2046 ? 2046 : gr);
            const size_t eb = (size_t)gr * HDIM;
            const f16x8 eh0 = *(const f16x8*)&Ehi[eb + quad * 8];
            const f16x8 eh1 = *(const f16x8*)&Ehi[eb + 32 + quad * 8];
            const f16x8 el0 = *(const f16x8*)&Elo[eb + quad * 8];
            const f16x8 el1 = *(const f16x8*)&Elo[eb + 32 + quad * 8];
            R[u]  = MFMAH(qh[0], eh0, R[u]);
            R[u]  = MFMAH(qh[1], eh1, R[u]);
            R[u]  = MFMAH(qh[0], el0, R[u]);
            R[u]  = MFMAH(qh[1], el1, R[u]);
            R2[u] = MFMAH(qm[0], eh0, R2[u]);
            R2[u] = MFMAH(qm[1], eh1, R2[u]);
        }
        #pragma unroll
        for (int u = 0; u < 5; u++)
            #pragma unroll
            for (int r = 0; r < 4; r++)
                R[u][r] = fmaf(R2[u][r], 9.765625e-4f, R[u][r]);
        // ---- skew gather via bpermute: need R[q][jj], jj = kl - q + 15 ----
        float bp[4][5];
        #pragma unroll
        for (int r = 0; r < 4; r++) {
            const int q = quad * 4 + r;
            const int srcl = (quad << 4) | ((c - q + 15) & 15);
            #pragma unroll
            for (int u = 0; u < 5; u++)
                bp[r][u] = __int_as_float(__builtin_amdgcn_ds_bpermute(srcl << 2, __float_as_int(R[u][r])));
        }
        float mkv[4];
        #pragma unroll
        for (int t = 0; t < 4; t++) mkv[t] = mkp[k0 + 16*t + c];
        float scv[4][4];
        float tmax[4] = {-3e38f, -3e38f, -3e38f, -3e38f};
        #pragma unroll
        for (int t = 0; t < 4; t++)
            #pragma unroll
            for (int r = 0; r < 4; r++) {
                const int q = quad*4 + r;
                const int jj = 16*t + c - q + 15;
                const float rv = ((jj >> 4) == t) ? bp[r][t] : bp[r][t+1];
                const float v = (S[t][r] + rv) * 0.125f + mkv[t];
                scv[t][r] = v;
                tmax[r] = fmaxf(tmax[r], v);
            }
        #pragma unroll
        for (int r = 0; r < 4; r++) {
            tmax[r] = fmaxf(tmax[r], __shfl_xor(tmax[r], 1));
            tmax[r] = fmaxf(tmax[r], __shfl_xor(tmax[r], 2));
            tmax[r] = fmaxf(tmax[r], __shfl_xor(tmax[r], 4));
            tmax[r] = fmaxf(tmax[r], __shfl_xor(tmax[r], 8));
        }
        float corr[4];
        #pragma unroll
        for (int r = 0; r < 4; r++) {
            const float mn = fmaxf(mrun[r], tmax[r]);
            corr[r] = __expf(mrun[r] - mn);
            mrun[r] = mn;
            lrun[r] *= corr[r];
        }
        #pragma unroll
        for (int dt = 0; dt < 4; dt++)
            #pragma unroll
            for (int r = 0; r < 4; r++) O[dt][r] *= corr[r];
        float psum[4] = {0.f, 0.f, 0.f, 0.f};
        #pragma unroll
        for (int t = 0; t < 4; t++)
            #pragma unroll
            for (int r = 0; r < 4; r++) {
                const float p = __expf(scv[t][r] - mrun[r]);
                psum[r] += p;
                _Float16 hp, lp;
                f16split(p, hp, lp);
                Phs[(w*16 + quad*4 + r)*72 + 16*t + c] = hp;
                Pls[(w*16 + quad*4 + r)*72 + 16*t + c] = lp;
            }
        #pragma unroll
        for (int r = 0; r < 4; r++) {
            psum[r] += __shfl_xor(psum[r], 1);
            psum[r] += __shfl_xor(psum[r], 2);
            psum[r] += __shfl_xor(psum[r], 4);
            psum[r] += __shfl_xor(psum[r], 8);
            lrun[r] += psum[r];
        }
        // ---- O += P V (3-pass) ----
        f16x8 pfh[2], pfl[2];
        #pragma unroll
        for (int s = 0; s < 2; s++) {
            pfh[s] = *(const f16x8*)&Phs[(w*16 + c)*72 + s*32 + quad*8];
            pfl[s] = *(const f16x8*)&Pls[(w*16 + c)*72 + s*32 + quad*8];
        }
        #pragma unroll
        for (int dt = 0; dt < 4; dt++)
            #pragma unroll
            for (int s = 0; s < 2; s++) {
                const f16x8 vhf = *(const f16x8*)&Vth[(16*dt + c)*72 + s*32 + quad*8];
                const f16x8 vlf = *(const f16x8*)&Vtl[(16*dt + c)*72 + s*32 + quad*8];
                O[dt] = MFMAH(pfh[s], vhf, O[dt]);
                O[dt] = MFMAH(pfl[s], vhf, O[dt]);
                O[dt] = MFMAH(pfh[s], vlf, O[dt]);
            }
        __syncthreads();
    }
    float inv[4];
    #pragma unroll
    for (int r = 0; r < 4; r++) inv[r] = 1.f / lrun[r];
    #pragma unroll
    for (int dt = 0; dt < 4; dt++)
        #pragma unroll
        for (int r = 0; r < 4; r++)
            ob[base + (size_t)(q0 + 16*w + quad*4 + r) * DMODEL + 16*dt + c] = O[dt][r] * inv[r];
}

extern "C" void kernel_launch(void* const* d_in, const int* in_sizes, int n_in,
                              void* d_out, int out_size, void* d_ws, size_t ws_size,
                              hipStream_t stream)
{
    const float* x       = (const float*)d_in[0];
    const float* mask_in = (const float*)d_in[1];
    const float* p_kf    = (const float*)d_in[2];
    const float* enc_w1  = (const float*)d_in[3];
    const float* enc_b1  = (const float*)d_in[4];
    const float* enc_a1  = (const float*)d_in[5];
    const float* enc_w2  = (const float*)d_in[6];
    const float* enc_b2  = (const float*)d_in[7];
    const float* enc_a2  = (const float*)d_in[8];
    const float* kf_w1   = (const float*)d_in[9];
    const float* kf_b1   = (const float*)d_in[10];
    const float* kf_a    = (const float*)d_in[11];
    const float* kf_w2   = (const float*)d_in[12];
    const float* kf_b2   = (const float*)d_in[13];
    const float* rel_w1  = (const float*)d_in[14];
    const float* rel_b1  = (const float*)d_in[15];
    const float* rel_a   = (const float*)d_in[16];
    const float* rel_w2  = (const float*)d_in[17];
    const float* rel_b2  = (const float*)d_in[18];
    const float* ln_g    = (const float*)d_in[19];
    const float* ln_b    = (const float*)d_in[20];
    const float* wq      = (const float*)d_in[21];
    const float* wk      = (const float*)d_in[22];
    const float* wv      = (const float*)d_in[23];
    const float* wo      = (const float*)d_in[24];
    const float* wob     = (const float*)d_in[25];
    const float* fw1     = (const float*)d_in[26];
    const float* fb1     = (const float*)d_in[27];
    const float* fa      = (const float*)d_in[28];
    const float* fw2     = (const float*)d_in[29];
    const float* fb2     = (const float*)d_in[30];
    const float* dw1     = (const float*)d_in[31];
    const float* db1     = (const float*)d_in[32];
    const float* da      = (const float*)d_in[33];
    const float* dw2     = (const float*)d_in[34];
    const float* db2     = (const float*)d_in[35];
    float* out = (float*)d_out;

    float* ws  = (float*)d_ws;
    float* h   = ws;
    float* hn  = h  + (size_t)NTOK * DMODEL;
    float* qb  = hn + (size_t)NTOK * DMODEL;
    float* kb  = qb + (size_t)NTOK * DMODEL;   // also holds pe_kf during encode
    float* vb  = kb + (size_t)NTOK * DMODEL;
    float* ob  = vb + (size_t)NTOK * DMODEL;
    float* mid = ob + (size_t)NTOK * DMODEL;   // NTOK*DFF
    _Float16* Ehi = (_Float16*)(mid + (size_t)NTOK * DFF);
    _Float16* Elo = Ehi + (size_t)2048 * HDIM;
    float* mk = (float*)(Elo + (size_t)2048 * HDIM);

    const dim3 blk256(256), blk64(64);
    const dim3 g512(512/64, NTOK/64);
    const dim3 g2048(2048/64, NTOK/64);
    const dim3 g256(256/64, NTOK/64);

    e_kernel<<<dim3(2047), blk64, 0, stream>>>(rel_w1, rel_b1, rel_a, rel_w2, rel_b2, Ehi, Elo);
    mask_kernel<<<dim3(NTOK), blk64, 0, stream>>>(mask_in, mk);
    kf1_kernel<<<dim3(NTOK*DMODEL/256), blk256, 0, stream>>>(p_kf, kf_w1, kf_b1, kf_a, qb);
    gemm_f32<<<g512, blk256, 0, stream>>>(qb, nullptr, 0, DMODEL, 0, kf_w2, kf_b2,
                                          nullptr, nullptr, kb, DMODEL, DMODEL);
    gemm_f32<<<g512, blk256, 0, stream>>>(x, mask_in, DMODEL, DMODEL, DMODEL, enc_w1, enc_b1,
                                          enc_a1, nullptr, mid, DMODEL, 2*DMODEL);
    gemm_f32<<<g512, blk256, 0, stream>>>(mid, nullptr, 0, DMODEL, 0, enc_w2, enc_b2,
                                          enc_a2, kb, h, DMODEL, DMODEL);

    for (int i = 0; i < NLAYER; i++) {
        const size_t wofs = (size_t)i * DMODEL * DMODEL;
        ln_kernel<<<dim3(NTOK), blk64, 0, stream>>>(h, ln_g, ln_b, hn);
        gemm_f32<<<g512, blk256, 0, stream>>>(hn, nullptr, 0, DMODEL, 0, wq + wofs, nullptr,
                                              nullptr, nullptr, qb, DMODEL, DMODEL);
        gemm_f32<<<g512, blk256, 0, stream>>>(hn, nullptr, 0, DMODEL, 0, wk + wofs, nullptr,
                                              nullptr, nullptr, kb, DMODEL, DMODEL);
        gemm_f32<<<g512, blk256, 0, stream>>>(hn, nullptr, 0, DMODEL, 0, wv + wofs, nullptr,
                                              nullptr, nullptr, vb, DMODEL, DMODEL);
        attn_mfma<<<dim3(TT/64, NHEAD, BB), blk256, 0, stream>>>(qb, kb, vb, Ehi, Elo, mk, ob);
        gemm_f32<<<g512, blk256, 0, stream>>>(ob, nullptr, 0, DMODEL, 0, wo + wofs, wob + (size_t)i*DMODEL,
                                              nullptr, h, h, DMODEL, DMODEL);
        ln_kernel<<<dim3(NTOK), blk64, 0, stream>>>(h, ln_g, ln_b, hn);
        gemm_f32<<<g2048, blk256, 0, stream>>>(hn, nullptr, 0, DMODEL, 0,
                                               fw1 + (size_t)i*DMODEL*DFF, fb1 + (size_t)i*DFF,
                                               fa + i, nullptr, mid, DFF, DMODEL);
        gemm_f32<<<g512, blk256, 0, stream>>>(mid, nullptr, 0, DFF, 0,
                                              fw2 + (size_t)i*DFF*DMODEL, fb2 + (size_t)i*DMODEL,
                                              nullptr, h, h, DMODEL, DFF);
    }
    gemm_f32<<<g512, blk256, 0, stream>>>(h, nullptr, 0, DMODEL, 0, dw1, db1,
                                          da, nullptr, qb, DMODEL, DMODEL);
    gemm_f32<<<g256, blk256, 0, stream>>>(qb, nullptr, 0, DMODEL, 0, dw2, db2,
                                          nullptr, nullptr, out, MFOUT, DMODEL);
}

// Round 4
// 2812.323 us; speedup vs baseline: 4.2913x; 1.3876x over previous
//
#include <hip/hip_runtime.h>
#include <cstddef>

#define BB 4
#define TT 1024
#define DMODEL 512
#define DFF 2048
#define NHEAD 8
#define HDIM 64
#define NTOK (BB*TT)
#define NLAYER 6
#define MFOUT 256

typedef __attribute__((ext_vector_type(8))) _Float16 f16x8;
typedef __attribute__((ext_vector_type(8))) short bf16x8;
typedef __attribute__((ext_vector_type(4))) float f32x4;
#define MFMAH(a,b,c) __builtin_amdgcn_mfma_f32_16x16x32_f16(a,b,c,0,0,0)
#define MFMAB(a,b,c) __builtin_amdgcn_mfma_f32_16x16x32_bf16(a,b,c,0,0,0)

union F16x4 { _Float16 h[4]; uint2 u; };

__device__ __forceinline__ void f16split(float v, _Float16& h, _Float16& l) {
    h = (_Float16)v;
    l = (_Float16)(v - (float)h);
}
__device__ __forceinline__ unsigned f2bf(float f) {
    union { float f; unsigned u; } v; v.f = f;
    return (v.u + 0x7FFFu + ((v.u >> 16) & 1u)) >> 16;
}
__device__ __forceinline__ float bf2f(unsigned h) {
    union { unsigned u; float f; } v; v.u = h << 16;
    return v.f;
}

// ---------------- MFMA GEMM, bf16 hi/lo 3-pass (fp32-equivalent accuracy) ----------------
// out[m][n] = (res ? res : 0) + act(sum_k A[m][k]*W[k][n] + bias[n])
// A*W ~= Ah*Wh + Al*Wh + Ah*Wl  (bf16 split has fp32 exponent range: no denormal issues;
// dropped Al*Wl term is ~2^-18 relative). Tile 128x64, 4 waves (2x2), BK=32.
__global__ __launch_bounds__(256, 2)
void gemm_mfma(const float* __restrict__ A, const float* __restrict__ A2, int K1, int lda, int lda2,
               const float* __restrict__ W, const float* __restrict__ bias,
               const float* __restrict__ alpha, const float* __restrict__ res,
               float* __restrict__ out, int N, int K)
{
    __shared__ __align__(16) short Ahs[128*40];  // [m][k] stride 40
    __shared__ __align__(16) short Als[128*40];
    __shared__ __align__(16) short Whs[64*40];   // [n][k] stride 40 (transposed)
    __shared__ __align__(16) short Wls[64*40];
    const int tid = threadIdx.x;
    const int lane = tid & 63;
    const int w = tid >> 6;
    const int wm = w >> 1, wn = w & 1;
    const int quad = lane >> 4, c = lane & 15;
    const int m0 = blockIdx.y * 128;
    const int n0 = blockIdx.x * 64;

    f32x4 acc[4][2];
    #pragma unroll
    for (int mi = 0; mi < 4; mi++)
        #pragma unroll
        for (int ni = 0; ni < 2; ni++) { acc[mi][ni][0]=0.f; acc[mi][ni][1]=0.f; acc[mi][ni][2]=0.f; acc[mi][ni][3]=0.f; }

    for (int k0 = 0; k0 < K; k0 += 32) {
        // ---- stage A tile 128x32 -> hi/lo ----
        #pragma unroll
        for (int i = 0; i < 4; i++) {
            const int idx = tid + i * 256;
            const int r = idx >> 3, c4 = (idx & 7) * 4;
            const int gk = k0 + c4;
            const float* src = (A2 != nullptr && gk >= K1)
                             ? &A2[(size_t)(m0 + r) * lda2 + (gk - K1)]
                             : &A [(size_t)(m0 + r) * lda  + gk];
            const float4 v = *(const float4*)src;
            const unsigned h0 = f2bf(v.x), h1 = f2bf(v.y), h2 = f2bf(v.z), h3 = f2bf(v.w);
            *(uint2*)&Ahs[r * 40 + c4] = make_uint2(h0 | (h1 << 16), h2 | (h3 << 16));
            const unsigned l0 = f2bf(v.x - bf2f(h0)), l1 = f2bf(v.y - bf2f(h1));
            const unsigned l2 = f2bf(v.z - bf2f(h2)), l3 = f2bf(v.w - bf2f(h3));
            *(uint2*)&Als[r * 40 + c4] = make_uint2(l0 | (l1 << 16), l2 | (l3 << 16));
        }
        // ---- stage W tile 32x64 -> hi/lo transposed [n][k] ----
        #pragma unroll
        for (int i = 0; i < 2; i++) {
            const int idx = tid + i * 256;
            const int r = idx >> 4, c4 = (idx & 15) * 4;
            const float4 v = *(const float4*)&W[(size_t)(k0 + r) * N + n0 + c4];
            const float va[4] = {v.x, v.y, v.z, v.w};
            #pragma unroll
            for (int j = 0; j < 4; j++) {
                const unsigned h = f2bf(va[j]);
                Whs[(c4 + j) * 40 + r] = (short)h;
                Wls[(c4 + j) * 40 + r] = (short)f2bf(va[j] - bf2f(h));
            }
        }
        __syncthreads();
        bf16x8 ah[4], al2[4], bh[2], bl2[2];
        #pragma unroll
        for (int mi = 0; mi < 4; mi++) {
            const int row = (wm * 64 + mi * 16 + c) * 40 + quad * 8;
            ah[mi]  = *(const bf16x8*)&Ahs[row];
            al2[mi] = *(const bf16x8*)&Als[row];
        }
        #pragma unroll
        for (int ni = 0; ni < 2; ni++) {
            const int row = (wn * 32 + ni * 16 + c) * 40 + quad * 8;
            bh[ni]  = *(const bf16x8*)&Whs[row];
            bl2[ni] = *(const bf16x8*)&Wls[row];
        }
        #pragma unroll
        for (int mi = 0; mi < 4; mi++)
            #pragma unroll
            for (int ni = 0; ni < 2; ni++) {
                acc[mi][ni] = MFMAB(ah[mi],  bh[ni],  acc[mi][ni]);
                acc[mi][ni] = MFMAB(al2[mi], bh[ni],  acc[mi][ni]);
                acc[mi][ni] = MFMAB(ah[mi],  bl2[ni], acc[mi][ni]);
            }
        __syncthreads();
    }
    const float alv = alpha ? alpha[0] : 0.f;
    #pragma unroll
    for (int mi = 0; mi < 4; mi++)
        #pragma unroll
        for (int ni = 0; ni < 2; ni++) {
            const int gn = n0 + wn * 32 + ni * 16 + c;
            const float bv = bias ? bias[gn] : 0.f;
            #pragma unroll
            for (int r = 0; r < 4; r++) {
                const int gm = m0 + wm * 64 + mi * 16 + quad * 4 + r;
                float v = acc[mi][ni][r] + bv;
                if (alpha) v = (v >= 0.f) ? v : alv * v;
                if (res) v += res[(size_t)gm * N + gn];
                out[(size_t)gm * N + gn] = v;
            }
        }
}

// ---------------- LayerNorm: one wave per token ----------------
__global__ __launch_bounds__(64)
void ln_kernel(const float* __restrict__ x, const float* __restrict__ g,
               const float* __restrict__ b, float* __restrict__ out)
{
    const int token = blockIdx.x;
    const int lane = threadIdx.x;
    const float* row = x + (size_t)token * DMODEL;
    float v[8];
    *(float4*)&v[0] = *(const float4*)&row[lane * 4];
    *(float4*)&v[4] = *(const float4*)&row[256 + lane * 4];
    float s = 0.f, s2 = 0.f;
    #pragma unroll
    for (int i = 0; i < 8; i++) { s += v[i]; s2 += v[i] * v[i]; }
    #pragma unroll
    for (int off = 1; off < 64; off <<= 1) {
        s  += __shfl_xor(s, off);
        s2 += __shfl_xor(s2, off);
    }
    const float mean = s * (1.f / DMODEL);
    const float var  = s2 * (1.f / DMODEL) - mean * mean;
    const float rstd = rsqrtf(var + 1e-5f);
    float* orow = out + (size_t)token * DMODEL;
    #pragma unroll
    for (int hh = 0; hh < 2; hh++) {
        const int base = hh * 256 + lane * 4;
        const float4 gv = *(const float4*)&g[base];
        const float4 bv = *(const float4*)&b[base];
        float4 o;
        o.x = (v[hh*4+0] - mean) * rstd * gv.x + bv.x;
        o.y = (v[hh*4+1] - mean) * rstd * gv.y + bv.y;
        o.z = (v[hh*4+2] - mean) * rstd * gv.z + bv.z;
        o.w = (v[hh*4+3] - mean) * rstd * gv.w + bv.w;
        *(float4*)&orow[base] = o;
    }
}

// ---------------- attention key-validity mask ----------------
__global__ __launch_bounds__(64)
void mask_kernel(const float* __restrict__ mask_in, float* __restrict__ mk)
{
    const int token = blockIdx.x;
    const int lane = threadIdx.x;
    const float* row = mask_in + (size_t)token * DMODEL;
    const float4 a = *(const float4*)&row[lane * 4];
    const float4 c = *(const float4*)&row[256 + lane * 4];
    float s = a.x + a.y + a.z + a.w + c.x + c.y + c.z + c.w;
    #pragma unroll
    for (int off = 1; off < 64; off <<= 1) s += __shfl_xor(s, off);
    if (lane == 0) mk[token] = (s > 0.f) ? 0.f : -1e9f;
}

// ---------------- relative position table E -> f16 hi/lo (2047, 64) ----------------
__global__ __launch_bounds__(64)
void e_kernel(const float* __restrict__ w1, const float* __restrict__ b1,
              const float* __restrict__ a1, const float* __restrict__ w2,
              const float* __restrict__ b2,
              _Float16* __restrict__ Ehi, _Float16* __restrict__ Elo)
{
    __shared__ float t1[DMODEL];
    const int r = blockIdx.x;
    const int lane = threadIdx.x;
    const float rel = (float)r - 1023.f;
    const float al = a1[0];
    for (int j = lane; j < DMODEL; j += 64) {
        float v = rel * w1[j] + b1[j];
        t1[j] = (v >= 0.f) ? v : al * v;
    }
    __syncthreads();
    float acc = b2[lane];
    for (int j = 0; j < DMODEL; j++)
        acc = fmaf(t1[j], w2[j * HDIM + lane], acc);
    _Float16 h, l;
    f16split(acc, h, l);
    Ehi[(size_t)r * HDIM + lane] = h;
    Elo[(size_t)r * HDIM + lane] = l;
}

// ---------------- keyframe encoder layer 1 (K=2) ----------------
__global__ __launch_bounds__(256)
void kf1_kernel(const float* __restrict__ p, const float* __restrict__ w1,
                const float* __restrict__ b1, const float* __restrict__ a1,
                float* __restrict__ out)
{
    const int idx = blockIdx.x * 256 + threadIdx.x;
    const int m = idx >> 9, n = idx & 511;
    float v = fmaf(p[m*2], w1[n], fmaf(p[m*2+1], w1[DMODEL + n], b1[n]));
    out[idx] = (v >= 0.f) ? v : a1[0] * v;
}

// ---------------- MFMA flash attention, f16 hi/lo precision ----------------
__global__ __launch_bounds__(256, 2)
void attn_mfma(const float* __restrict__ qb, const float* __restrict__ kb,
               const float* __restrict__ vb, const _Float16* __restrict__ Ehi,
               const _Float16* __restrict__ Elo, const float* __restrict__ mk,
               float* __restrict__ ob)
{
    __shared__ __align__(16) _Float16 Ks [64*72];
    __shared__ __align__(16) _Float16 Vth[64*72];
    __shared__ __align__(16) _Float16 Vtl[64*72];
    __shared__ __align__(16) _Float16 Phs[64*72];
    __shared__ __align__(16) _Float16 Pls[64*72];

    const int tid = threadIdx.x;
    const int lane = tid & 63;
    const int w = tid >> 6;
    const int quad = lane >> 4;
    const int c = lane & 15;
    const int q0 = blockIdx.x * 64;
    const int hh = blockIdx.y;
    const int bb = blockIdx.z;
    const size_t base = (size_t)bb * TT * DMODEL + (size_t)hh * HDIM;
    const float* mkp = mk + bb * TT;

    #pragma unroll
    for (int i = 0; i < 4; i++) {
        const int f4 = tid + i * 256;
        const int r = f4 >> 4, dc = (f4 & 15) * 4;
        const float4 v = *(const float4*)&qb[base + (size_t)(q0 + r) * DMODEL + dc];
        F16x4 ph, pm;
        const float vv[4] = {v.x, v.y, v.z, v.w};
        #pragma unroll
        for (int j = 0; j < 4; j++) {
            ph.h[j] = (_Float16)vv[j];
            pm.h[j] = (_Float16)((vv[j] - (float)ph.h[j]) * 1024.f);
        }
        *(uint2*)&Ks [r * 72 + dc] = ph.u;
        *(uint2*)&Vth[r * 72 + dc] = pm.u;
    }
    __syncthreads();
    f16x8 qh[2], qm[2];
    #pragma unroll
    for (int s = 0; s < 2; s++) {
        qh[s] = *(const f16x8*)&Ks [(16 * w + c) * 72 + s * 32 + quad * 8];
        qm[s] = *(const f16x8*)&Vth[(16 * w + c) * 72 + s * 32 + quad * 8];
    }
    __syncthreads();

    f32x4 O[4];
    #pragma unroll
    for (int dt = 0; dt < 4; dt++) { O[dt][0]=0.f; O[dt][1]=0.f; O[dt][2]=0.f; O[dt][3]=0.f; }
    float mrun[4] = {-1e30f, -1e30f, -1e30f, -1e30f};
    float lrun[4] = {0.f, 0.f, 0.f, 0.f};
    const int Jb = 48 - 16 * w;

    for (int kt = 0; kt < 16; kt++) {
        const int k0 = kt * 64;
        const size_t kvbase = base + (size_t)k0 * DMODEL;
        const int rbase = k0 - q0 + 960;
        #pragma unroll
        for (int i = 0; i < 4; i++) {
            const int f4 = tid + i * 256;
            const int r = f4 >> 4, dc = (f4 & 15) * 4;
            const float4 kv = *(const float4*)&kb[kvbase + (size_t)r * DMODEL + dc];
            F16x4 pk;
            pk.h[0] = (_Float16)kv.x; pk.h[1] = (_Float16)kv.y;
            pk.h[2] = (_Float16)kv.z; pk.h[3] = (_Float16)kv.w;
            *(uint2*)&Ks[r * 72 + dc] = pk.u;
            const float4 vv = *(const float4*)&vb[kvbase + (size_t)r * DMODEL + dc];
            const float va[4] = {vv.x, vv.y, vv.z, vv.w};
            #pragma unroll
            for (int j = 0; j < 4; j++) {
                _Float16 vh_, vl_;
                f16split(va[j], vh_, vl_);
                Vth[(dc + j) * 72 + r] = vh_;
                Vtl[(dc + j) * 72 + r] = vl_;
            }
        }
        __syncthreads();

        f32x4 S[4];
        #pragma unroll
        for (int t = 0; t < 4; t++) { S[t][0]=0.f; S[t][1]=0.f; S[t][2]=0.f; S[t][3]=0.f; }
        #pragma unroll
        for (int t = 0; t < 4; t++)
            #pragma unroll
            for (int s = 0; s < 2; s++) {
                const f16x8 kf = *(const f16x8*)&Ks[(16*t + c) * 72 + s*32 + quad*8];
                S[t] = MFMAH(qh[s], kf, S[t]);
            }
        f32x4 R[5], R2[5];
        #pragma unroll
        for (int u = 0; u < 5; u++) {
            R[u][0]=0.f; R[u][1]=0.f; R[u][2]=0.f; R[u][3]=0.f;
            R2[u][0]=0.f; R2[u][1]=0.f; R2[u][2]=0.f; R2[u][3]=0.f;
        }
        #pragma unroll
        for (int u = 0; u < 5; u++) {
            int gr = rbase + Jb + 16 * u + c;
            gr = gr < 0 ? 0 : (gr > 2046 ? 2046 : gr);
            const size_t eb = (size_t)gr * HDIM;
            const f16x8 eh0 = *(const f16x8*)&Ehi[eb + quad * 8];
            const f16x8 eh1 = *(const f16x8*)&Ehi[eb + 32 + quad * 8];
            const f16x8 el0 = *(const f16x8*)&Elo[eb + quad * 8];
            const f16x8 el1 = *(const f16x8*)&Elo[eb + 32 + quad * 8];
            R[u]  = MFMAH(qh[0], eh0, R[u]);
            R[u]  = MFMAH(qh[1], eh1, R[u]);
            R[u]  = MFMAH(qh[0], el0, R[u]);
            R[u]  = MFMAH(qh[1], el1, R[u]);
            R2[u] = MFMAH(qm[0], eh0, R2[u]);
            R2[u] = MFMAH(qm[1], eh1, R2[u]);
        }
        #pragma unroll
        for (int u = 0; u < 5; u++)
            #pragma unroll
            for (int r = 0; r < 4; r++)
                R[u][r] = fmaf(R2[u][r], 9.765625e-4f, R[u][r]);
        float bp[4][5];
        #pragma unroll
        for (int r = 0; r < 4; r++) {
            const int q = quad * 4 + r;
            const int srcl = (quad << 4) | ((c - q + 15) & 15);
            #pragma unroll
            for (int u = 0; u < 5; u++)
                bp[r][u] = __int_as_float(__builtin_amdgcn_ds_bpermute(srcl << 2, __float_as_int(R[u][r])));
        }
        float mkv[4];
        #pragma unroll
        for (int t = 0; t < 4; t++) mkv[t] = mkp[k0 + 16*t + c];
        float scv[4][4];
        float tmax[4] = {-3e38f, -3e38f, -3e38f, -3e38f};
        #pragma unroll
        for (int t = 0; t < 4; t++)
            #pragma unroll
            for (int r = 0; r < 4; r++) {
                const int q = quad*4 + r;
                const int jj = 16*t + c - q + 15;
                const float rv = ((jj >> 4) == t) ? bp[r][t] : bp[r][t+1];
                const float v = (S[t][r] + rv) * 0.125f + mkv[t];
                scv[t][r] = v;
                tmax[r] = fmaxf(tmax[r], v);
            }
        #pragma unroll
        for (int r = 0; r < 4; r++) {
            tmax[r] = fmaxf(tmax[r], __shfl_xor(tmax[r], 1));
            tmax[r] = fmaxf(tmax[r], __shfl_xor(tmax[r], 2));
            tmax[r] = fmaxf(tmax[r], __shfl_xor(tmax[r], 4));
            tmax[r] = fmaxf(tmax[r], __shfl_xor(tmax[r], 8));
        }
        float corr[4];
        #pragma unroll
        for (int r = 0; r < 4; r++) {
            const float mn = fmaxf(mrun[r], tmax[r]);
            corr[r] = __expf(mrun[r] - mn);
            mrun[r] = mn;
            lrun[r] *= corr[r];
        }
        #pragma unroll
        for (int dt = 0; dt < 4; dt++)
            #pragma unroll
            for (int r = 0; r < 4; r++) O[dt][r] *= corr[r];
        float psum[4] = {0.f, 0.f, 0.f, 0.f};
        #pragma unroll
        for (int t = 0; t < 4; t++)
            #pragma unroll
            for (int r = 0; r < 4; r++) {
                const float p = __expf(scv[t][r] - mrun[r]);
                psum[r] += p;
                _Float16 hp, lp;
                f16split(p, hp, lp);
                Phs[(w*16 + quad*4 + r)*72 + 16*t + c] = hp;
                Pls[(w*16 + quad*4 + r)*72 + 16*t + c] = lp;
            }
        #pragma unroll
        for (int r = 0; r < 4; r++) {
            psum[r] += __shfl_xor(psum[r], 1);
            psum[r] += __shfl_xor(psum[r], 2);
            psum[r] += __shfl_xor(psum[r], 4);
            psum[r] += __shfl_xor(psum[r], 8);
            lrun[r] += psum[r];
        }
        f16x8 pfh[2], pfl[2];
        #pragma unroll
        for (int s = 0; s < 2; s++) {
            pfh[s] = *(const f16x8*)&Phs[(w*16 + c)*72 + s*32 + quad*8];
            pfl[s] = *(const f16x8*)&Pls[(w*16 + c)*72 + s*32 + quad*8];
        }
        #pragma unroll
        for (int dt = 0; dt < 4; dt++)
            #pragma unroll
            for (int s = 0; s < 2; s++) {
                const f16x8 vhf = *(const f16x8*)&Vth[(16*dt + c)*72 + s*32 + quad*8];
                const f16x8 vlf = *(const f16x8*)&Vtl[(16*dt + c)*72 + s*32 + quad*8];
                O[dt] = MFMAH(pfh[s], vhf, O[dt]);
                O[dt] = MFMAH(pfl[s], vhf, O[dt]);
                O[dt] = MFMAH(pfh[s], vlf, O[dt]);
            }
        __syncthreads();
    }
    float inv[4];
    #pragma unroll
    for (int r = 0; r < 4; r++) inv[r] = 1.f / lrun[r];
    #pragma unroll
    for (int dt = 0; dt < 4; dt++)
        #pragma unroll
        for (int r = 0; r < 4; r++)
            ob[base + (size_t)(q0 + 16*w + quad*4 + r) * DMODEL + 16*dt + c] = O[dt][r] * inv[r];
}

extern "C" void kernel_launch(void* const* d_in, const int* in_sizes, int n_in,
                              void* d_out, int out_size, void* d_ws, size_t ws_size,
                              hipStream_t stream)
{
    const float* x       = (const float*)d_in[0];
    const float* mask_in = (const float*)d_in[1];
    const float* p_kf    = (const float*)d_in[2];
    const float* enc_w1  = (const float*)d_in[3];
    const float* enc_b1  = (const float*)d_in[4];
    const float* enc_a1  = (const float*)d_in[5];
    const float* enc_w2  = (const float*)d_in[6];
    const float* enc_b2  = (const float*)d_in[7];
    const float* enc_a2  = (const float*)d_in[8];
    const float* kf_w1   = (const float*)d_in[9];
    const float* kf_b1   = (const float*)d_in[10];
    const float* kf_a    = (const float*)d_in[11];
    const float* kf_w2   = (const float*)d_in[12];
    const float* kf_b2   = (const float*)d_in[13];
    const float* rel_w1  = (const float*)d_in[14];
    const float* rel_b1  = (const float*)d_in[15];
    const float* rel_a   = (const float*)d_in[16];
    const float* rel_w2  = (const float*)d_in[17];
    const float* rel_b2  = (const float*)d_in[18];
    const float* ln_g    = (const float*)d_in[19];
    const float* ln_b    = (const float*)d_in[20];
    const float* wq      = (const float*)d_in[21];
    const float* wk      = (const float*)d_in[22];
    const float* wv      = (const float*)d_in[23];
    const float* wo      = (const float*)d_in[24];
    const float* wob     = (const float*)d_in[25];
    const float* fw1     = (const float*)d_in[26];
    const float* fb1     = (const float*)d_in[27];
    const float* fa      = (const float*)d_in[28];
    const float* fw2     = (const float*)d_in[29];
    const float* fb2     = (const float*)d_in[30];
    const float* dw1     = (const float*)d_in[31];
    const float* db1     = (const float*)d_in[32];
    const float* da      = (const float*)d_in[33];
    const float* dw2     = (const float*)d_in[34];
    const float* db2     = (const float*)d_in[35];
    float* out = (float*)d_out;

    float* ws  = (float*)d_ws;
    float* h   = ws;
    float* hn  = h  + (size_t)NTOK * DMODEL;
    float* qb  = hn + (size_t)NTOK * DMODEL;
    float* kb  = qb + (size_t)NTOK * DMODEL;
    float* vb  = kb + (size_t)NTOK * DMODEL;
    float* ob  = vb + (size_t)NTOK * DMODEL;
    float* mid = ob + (size_t)NTOK * DMODEL;
    _Float16* Ehi = (_Float16*)(mid + (size_t)NTOK * DFF);
    _Float16* Elo = Ehi + (size_t)2048 * HDIM;
    float* mk = (float*)(Elo + (size_t)2048 * HDIM);

    const dim3 blk256(256), blk64(64);
    const dim3 g512(512/64, NTOK/128);
    const dim3 g2048(2048/64, NTOK/128);
    const dim3 g256(256/64, NTOK/128);

    e_kernel<<<dim3(2047), blk64, 0, stream>>>(rel_w1, rel_b1, rel_a, rel_w2, rel_b2, Ehi, Elo);
    mask_kernel<<<dim3(NTOK), blk64, 0, stream>>>(mask_in, mk);
    kf1_kernel<<<dim3(NTOK*DMODEL/256), blk256, 0, stream>>>(p_kf, kf_w1, kf_b1, kf_a, qb);
    gemm_mfma<<<g512, blk256, 0, stream>>>(qb, nullptr, 0, DMODEL, 0, kf_w2, kf_b2,
                                           nullptr, nullptr, kb, DMODEL, DMODEL);
    gemm_mfma<<<g512, blk256, 0, stream>>>(x, mask_in, DMODEL, DMODEL, DMODEL, enc_w1, enc_b1,
                                           enc_a1, nullptr, mid, DMODEL, 2*DMODEL);
    gemm_mfma<<<g512, blk256, 0, stream>>>(mid, nullptr, 0, DMODEL, 0, enc_w2, enc_b2,
                                           enc_a2, kb, h, DMODEL, DMODEL);

    for (int i = 0; i < NLAYER; i++) {
        const size_t wofs = (size_t)i * DMODEL * DMODEL;
        ln_kernel<<<dim3(NTOK), blk64, 0, stream>>>(h, ln_g, ln_b, hn);
        gemm_mfma<<<g512, blk256, 0, stream>>>(hn, nullptr, 0, DMODEL, 0, wq + wofs, nullptr,
                                               nullptr, nullptr, qb, DMODEL, DMODEL);
        gemm_mfma<<<g512, blk256, 0, stream>>>(hn, nullptr, 0, DMODEL, 0, wk + wofs, nullptr,
                                               nullptr, nullptr, kb, DMODEL, DMODEL);
        gemm_mfma<<<g512, blk256, 0, stream>>>(hn, nullptr, 0, DMODEL, 0, wv + wofs, nullptr,
                                               nullptr, nullptr, vb, DMODEL, DMODEL);
        attn_mfma<<<dim3(TT/64, NHEAD, BB), blk256, 0, stream>>>(qb, kb, vb, Ehi, Elo, mk, ob);
        gemm_mfma<<<g512, blk256, 0, stream>>>(ob, nullptr, 0, DMODEL, 0, wo + wofs, wob + (size_t)i*DMODEL,
                                               nullptr, h, h, DMODEL, DMODEL);
        ln_kernel<<<dim3(NTOK), blk64, 0, stream>>>(h, ln_g, ln_b, hn);
        gemm_mfma<<<g2048, blk256, 0, stream>>>(hn, nullptr, 0, DMODEL, 0,
                                                fw1 + (size_t)i*DMODEL*DFF, fb1 + (size_t)i*DFF,
                                                fa + i, nullptr, mid, DFF, DMODEL);
        gemm_mfma<<<g512, blk256, 0, stream>>>(mid, nullptr, 0, DFF, 0,
                                               fw2 + (size_t)i*DFF*DMODEL, fb2 + (size_t)i*DMODEL,
                                               nullptr, h, h, DMODEL, DFF);
    }
    gemm_mfma<<<g512, blk256, 0, stream>>>(h, nullptr, 0, DMODEL, 0, dw1, db1,
                                           da, nullptr, qb, DMODEL, DMODEL);
    gemm_mfma<<<g256, blk256, 0, stream>>>(qb, nullptr, 0, DMODEL, 0, dw2, db2,
                                           nullptr, nullptr, out, MFOUT, DMODEL);
}